// Round 1
// baseline (430.135 us; speedup 1.0000x reference)
//
#include <hip/hip_runtime.h>
#include <math.h>

// Problem constants
#define B_ROWS 65536
#define D_DIM  768
#define S_DIM  64
#define T_PTS  17

// Workspace layout (float offsets). Accumulators (must be zeroed) live in
// the first 4096 floats; proj [65536 x 64] follows. Total ~16.02 MiB.
#define WS_COLSUM 0       // 768  : per-dim sum of z
#define WS_COLSQ  768     // 768  : per-dim sumsq of z
#define WS_PSUM   1536    // 64   : per-col sum of proj
#define WS_PSQ    1600    // 64   : per-col sumsq of proj
#define WS_ECFR   1664    // 17*64: sum cos
#define WS_ECFI   2752    // 17*64: sum sin
#define WS_INVN   3840    // 64   : 1/||dir_col||
#define WS_MEAN   3904    // 64
#define WS_SCALE  3968    // 64
#define WS_PROJ   4096    // 65536*64

// ---------------------------------------------------------------- dirs norms
__global__ void norm_kernel(const float* __restrict__ dirs, float* __restrict__ ws) {
    int s = blockIdx.x;      // 64 blocks, one per column
    int t = threadIdx.x;     // 64 threads
    float sum = 0.f;
    #pragma unroll
    for (int j = 0; j < D_DIM / 64; ++j) {
        float v = dirs[(size_t)(t + j * 64) * S_DIM + s];
        sum += v * v;
    }
    #pragma unroll
    for (int off = 32; off > 0; off >>= 1)
        sum += __shfl_down(sum, off, 64);
    if (t == 0) ws[WS_INVN + s] = 1.0f / sqrtf(sum);
}

// ------------------------------------------------------- per-dim z statistics
// 1024 blocks x 256 threads; block handles 64 rows; thread t owns dims t, t+256, t+512
__global__ __launch_bounds__(256) void colstats_kernel(const float* __restrict__ z,
                                                       float* __restrict__ ws) {
    int t = threadIdx.x;
    size_t base = (size_t)blockIdx.x * 64 * D_DIM;
    float s0 = 0, s1 = 0, s2 = 0, q0 = 0, q1 = 0, q2 = 0;
    #pragma unroll 4
    for (int r = 0; r < 64; ++r) {
        const float* p = z + base + (size_t)r * D_DIM;
        float a = p[t], b = p[t + 256], c = p[t + 512];
        s0 += a; q0 = fmaf(a, a, q0);
        s1 += b; q1 = fmaf(b, b, q1);
        s2 += c; q2 = fmaf(c, c, q2);
    }
    atomicAdd(&ws[WS_COLSUM + t],       s0);
    atomicAdd(&ws[WS_COLSUM + t + 256], s1);
    atomicAdd(&ws[WS_COLSUM + t + 512], s2);
    atomicAdd(&ws[WS_COLSQ + t],        q0);
    atomicAdd(&ws[WS_COLSQ + t + 256],  q1);
    atomicAdd(&ws[WS_COLSQ + t + 512],  q2);
}

// --------------------------------------------------------------- proj = z @ dn
// 1024 blocks (64 rows each) x 256 threads. Tile 64x64, each thread 4x4.
// LDS: zsT[64 k][68 rows] (transposed, padded) + dsm[64 k][64 s].
__global__ __launch_bounds__(256) void gemm_kernel(const float* __restrict__ z,
                                                   const float* __restrict__ dirs,
                                                   float* __restrict__ ws) {
    __shared__ float smem[4352 + 4096];
    float* zsT = smem;          // [k][row], row stride 68
    float* dsm = smem + 4352;   // [k][s],   row stride 64
    float* proj = ws + WS_PROJ;

    int tid = threadIdx.x;
    int tx = tid & 15, ty = tid >> 4;     // tx -> 4 cols, ty -> 4 rows
    size_t rowbase = (size_t)blockIdx.x * 64;

    float4 invn4 = *reinterpret_cast<const float4*>(ws + WS_INVN + tx * 4);
    float acc[4][4] = {};

    for (int c = 0; c < D_DIM / 64; ++c) {
        int kc = c * 64;
        #pragma unroll
        for (int j = 0; j < 4; ++j) {
            int rr = ty + 16 * j;   // row for z staging, k for dirs staging
            float4 v = *reinterpret_cast<const float4*>(
                z + (rowbase + rr) * D_DIM + kc + tx * 4);
            zsT[(tx * 4 + 0) * 68 + rr] = v.x;
            zsT[(tx * 4 + 1) * 68 + rr] = v.y;
            zsT[(tx * 4 + 2) * 68 + rr] = v.z;
            zsT[(tx * 4 + 3) * 68 + rr] = v.w;
            float4 dv = *reinterpret_cast<const float4*>(
                dirs + (size_t)(kc + rr) * S_DIM + tx * 4);
            dv.x *= invn4.x; dv.y *= invn4.y; dv.z *= invn4.z; dv.w *= invn4.w;
            *reinterpret_cast<float4*>(dsm + rr * 64 + tx * 4) = dv;
        }
        __syncthreads();
        #pragma unroll 8
        for (int k = 0; k < 64; ++k) {
            float4 a4 = *reinterpret_cast<const float4*>(zsT + k * 68 + ty * 4);
            float4 b4 = *reinterpret_cast<const float4*>(dsm + k * 64 + tx * 4);
            float av[4] = {a4.x, a4.y, a4.z, a4.w};
            float bv[4] = {b4.x, b4.y, b4.z, b4.w};
            #pragma unroll
            for (int i = 0; i < 4; ++i)
                #pragma unroll
                for (int j = 0; j < 4; ++j)
                    acc[i][j] = fmaf(av[i], bv[j], acc[i][j]);
        }
        __syncthreads();
    }

    // write proj (coalesced float4 per row)
    #pragma unroll
    for (int i = 0; i < 4; ++i) {
        float4 v = {acc[i][0], acc[i][1], acc[i][2], acc[i][3]};
        *reinterpret_cast<float4*>(proj + (rowbase + ty * 4 + i) * S_DIM + tx * 4) = v;
    }

    // per-column partials for proj stats (fused epilogue)
    float cs[4] = {}, cq[4] = {};
    #pragma unroll
    for (int i = 0; i < 4; ++i)
        #pragma unroll
        for (int j = 0; j < 4; ++j) {
            cs[j] += acc[i][j];
            cq[j] = fmaf(acc[i][j], acc[i][j], cq[j]);
        }
    __syncthreads();               // safe to reuse smem
    float* reds = smem;            // [16][64]
    float* redq = smem + 1024;     // [16][64]
    #pragma unroll
    for (int j = 0; j < 4; ++j) {
        reds[ty * 64 + tx * 4 + j] = cs[j];
        redq[ty * 64 + tx * 4 + j] = cq[j];
    }
    __syncthreads();
    if (tid < 64) {
        float ssum = 0, qsum = 0;
        #pragma unroll
        for (int r = 0; r < 16; ++r) {
            ssum += reds[r * 64 + tid];
            qsum += redq[r * 64 + tid];
        }
        atomicAdd(&ws[WS_PSUM + tid], ssum);
        atomicAdd(&ws[WS_PSQ + tid],  qsum);
    }
}

// ------------------------------------------------- finalize proj column stats
__global__ void finalize_kernel(float* __restrict__ ws) {
    int s = threadIdx.x;  // 64
    float sum = ws[WS_PSUM + s], sq = ws[WS_PSQ + s];
    float mean = sum / (float)B_ROWS;
    float var = (sq - (float)B_ROWS * mean * mean) / (float)(B_ROWS - 1);
    var = fmaxf(var, 0.f);
    float sd = sqrtf(var);
    ws[WS_MEAN + s]  = mean;
    ws[WS_SCALE + s] = 1.0f / (sd + 1e-8f);
}

// ------------------------------------------------------------------ ECF sums
// 1024 blocks (64 rows) x 256 threads; thread = (s = tid&63, r = tid>>6).
// One sincos + 16 complex rotations per element (angle-addition recurrence).
__global__ __launch_bounds__(256) void ecf_kernel(float* __restrict__ ws) {
    const float* proj = ws + WS_PROJ;
    int tid = threadIdx.x;
    int s = tid & 63, r = tid >> 6;
    float mean  = ws[WS_MEAN + s];
    float scale = ws[WS_SCALE + s];
    const float dt = 2.0f / 17.0f;

    float ar[T_PTS] = {}, ai[T_PTS] = {};
    size_t base = (size_t)blockIdx.x * 64;
    for (int i = 0; i < 16; ++i) {
        size_t row = base + i * 4 + r;
        float p  = proj[row * S_DIM + s];
        float ph = (p - mean) * scale;
        float a  = dt * ph;
        float s1, c1;
        __sincosf(a, &s1, &c1);
        float cc = c1, sn = s1;
        ar[0] += cc; ai[0] += sn;
        #pragma unroll
        for (int k = 1; k < T_PTS; ++k) {
            float cn = cc * c1 - sn * s1;
            sn = fmaf(sn, c1, cc * s1);
            cc = cn;
            ar[k] += cc; ai[k] += sn;
        }
    }

    // reduce r=1..3 partials into r=0 via LDS, then one atomic per (t,s)
    __shared__ float red[3 * 2 * T_PTS * 64];
    if (r > 0) {
        float* dst = red + (r - 1) * (2 * T_PTS * 64);
        #pragma unroll
        for (int k = 0; k < T_PTS; ++k) {
            dst[k * 64 + s]               = ar[k];
            dst[T_PTS * 64 + k * 64 + s]  = ai[k];
        }
    }
    __syncthreads();
    if (r == 0) {
        const int STRIDE = 2 * T_PTS * 64;
        #pragma unroll
        for (int k = 0; k < T_PTS; ++k) {
            float vr = ar[k] + red[k * 64 + s] + red[STRIDE + k * 64 + s]
                             + red[2 * STRIDE + k * 64 + s];
            float vi = ai[k] + red[T_PTS * 64 + k * 64 + s]
                             + red[STRIDE + T_PTS * 64 + k * 64 + s]
                             + red[2 * STRIDE + T_PTS * 64 + k * 64 + s];
            atomicAdd(&ws[WS_ECFR + k * 64 + s], vr);
            atomicAdd(&ws[WS_ECFI + k * 64 + s], vi);
        }
    }
}

// ------------------------------------------------------------------ final loss
__global__ __launch_bounds__(256) void loss_kernel(const float* __restrict__ ws,
                                                   float* __restrict__ out) {
    int tid = threadIdx.x;
    double local = 0.0;
    // var_floor
    for (int d = tid; d < D_DIM; d += 256) {
        double sum = (double)ws[WS_COLSUM + d];
        double sq  = (double)ws[WS_COLSQ + d];
        double mean = sum / 65536.0;
        double var  = (sq - 65536.0 * mean * mean) / 65535.0;
        if (var < 0) var = 0;
        double rl = 1.0 - sqrt(var);
        if (rl < 0) rl = 0;
        local += rl / 768.0;
    }
    // ECF part
    const double dt = 2.0 / 17.0;
    for (int idx = tid; idx < T_PTS * 64; idx += 256) {
        int i = idx >> 6;
        double t   = dt * (i + 1);
        double tcf = exp(-0.5 * t * t);
        double w   = (i == 0 || i == T_PTS - 1) ? dt * 0.5 : dt;
        double er = (double)ws[WS_ECFR + idx] / 65536.0;
        double ei = (double)ws[WS_ECFI + idx] / 65536.0;
        double term = er * er + ei * ei - 2.0 * er * tcf + tcf * tcf;
        local += w * term / 64.0;
    }
    __shared__ double red[256];
    red[tid] = local;
    __syncthreads();
    for (int off = 128; off > 0; off >>= 1) {
        if (tid < off) red[tid] += red[tid + off];
        __syncthreads();
    }
    if (tid == 0) out[0] = (float)red[0];
}

extern "C" void kernel_launch(void* const* d_in, const int* in_sizes, int n_in,
                              void* d_out, int out_size, void* d_ws, size_t ws_size,
                              hipStream_t stream) {
    const float* z    = (const float*)d_in[0];  // [65536, 768]
    const float* dirs = (const float*)d_in[1];  // [768, 64]
    float* out = (float*)d_out;                 // scalar fp32
    float* ws  = (float*)d_ws;                  // needs ~16.02 MiB

    // zero the accumulator region (first 4096 floats)
    hipMemsetAsync(ws, 0, 4096 * sizeof(float), stream);

    norm_kernel<<<S_DIM, 64, 0, stream>>>(dirs, ws);
    colstats_kernel<<<B_ROWS / 64, 256, 0, stream>>>(z, ws);
    gemm_kernel<<<B_ROWS / 64, 256, 0, stream>>>(z, dirs, ws);
    finalize_kernel<<<1, 64, 0, stream>>>(ws);
    ecf_kernel<<<B_ROWS / 64, 256, 0, stream>>>(ws);
    loss_kernel<<<1, 256, 0, stream>>>(ws, out);
}

// Round 2
// 397.699 us; speedup vs baseline: 1.0816x; 1.0816x over previous
//
#include <hip/hip_runtime.h>
#include <math.h>

// Problem constants
#define B_ROWS 65536
#define D_DIM  768
#define S_DIM  64
#define T_PTS  17

// Workspace layout (float offsets). Accumulators (zeroed by norm_kernel) in
// first 3840 floats; proj [65536 x 64] follows. Total ~16.02 MiB.
#define WS_COLSUM 0       // 768  : per-dim sum of z
#define WS_COLSQ  768     // 768  : per-dim sumsq of z
#define WS_PSUM   1536    // 64   : per-col sum of proj
#define WS_PSQ    1600    // 64   : per-col sumsq of proj
#define WS_ECFR   1664    // 17*64: sum cos
#define WS_ECFI   2752    // 17*64: sum sin  (ends at 3840)
#define WS_INVN   3840    // 64   : 1/||dir_col||
#define WS_PROJ   4096    // 65536*64

// ------------------------------------------- dirs norms + zero accumulators
// 64 blocks x 64 threads. Blocks 0..59 also zero the accumulator region
// (0..3839); WS_INVN (3840..3903) is only written below, so no race.
__global__ void norm_kernel(const float* __restrict__ dirs, float* __restrict__ ws) {
    int s = blockIdx.x;
    int t = threadIdx.x;
    if (s < 60) ws[s * 64 + t] = 0.f;   // zero accumulators every call
    float sum = 0.f;
    #pragma unroll
    for (int j = 0; j < D_DIM / 64; ++j) {
        float v = dirs[(size_t)(t + j * 64) * S_DIM + s];
        sum += v * v;
    }
    #pragma unroll
    for (int off = 32; off > 0; off >>= 1)
        sum += __shfl_down(sum, off, 64);
    if (t == 0) ws[WS_INVN + s] = 1.0f / sqrtf(sum);
}

// ------------------------------- fused proj = z @ dn  +  per-dim z statistics
// 1024 blocks (64 rows each) x 256 threads. Tile 64x64, each thread 4x4.
// z is read from HBM exactly ONCE; per-dim sum/sumsq computed during staging.
__global__ __launch_bounds__(256) void gemm_kernel(const float* __restrict__ z,
                                                   const float* __restrict__ dirs,
                                                   float* __restrict__ ws) {
    __shared__ float smem[4352 + 4096];   // zsT [64k][68r pad] + dsm [64k][64s]
    __shared__ float red_s[16 * 64];      // colstat partials: [ty][k_local]
    __shared__ float red_q[16 * 64];
    float* zsT = smem;
    float* dsm = smem + 4352;
    float* proj = ws + WS_PROJ;

    int tid = threadIdx.x;
    int tx = tid & 15, ty = tid >> 4;     // tx -> 4 cols, ty -> 4 rows
    size_t rowbase = (size_t)blockIdx.x * 64;

    float4 invn4 = *reinterpret_cast<const float4*>(ws + WS_INVN + tx * 4);
    float acc[4][4] = {};

    for (int c = 0; c < D_DIM / 64; ++c) {
        int kc = c * 64;
        float ps0 = 0, ps1 = 0, ps2 = 0, ps3 = 0;
        float pq0 = 0, pq1 = 0, pq2 = 0, pq3 = 0;
        #pragma unroll
        for (int j = 0; j < 4; ++j) {
            int rr = ty + 16 * j;   // row for z staging, k for dirs staging
            float4 v = *reinterpret_cast<const float4*>(
                z + (rowbase + rr) * D_DIM + kc + tx * 4);
            zsT[(tx * 4 + 0) * 68 + rr] = v.x;
            zsT[(tx * 4 + 1) * 68 + rr] = v.y;
            zsT[(tx * 4 + 2) * 68 + rr] = v.z;
            zsT[(tx * 4 + 3) * 68 + rr] = v.w;
            ps0 += v.x; pq0 = fmaf(v.x, v.x, pq0);
            ps1 += v.y; pq1 = fmaf(v.y, v.y, pq1);
            ps2 += v.z; pq2 = fmaf(v.z, v.z, pq2);
            ps3 += v.w; pq3 = fmaf(v.w, v.w, pq3);
            float4 dv = *reinterpret_cast<const float4*>(
                dirs + (size_t)(kc + rr) * S_DIM + tx * 4);
            dv.x *= invn4.x; dv.y *= invn4.y; dv.z *= invn4.z; dv.w *= invn4.w;
            *reinterpret_cast<float4*>(dsm + rr * 64 + tx * 4) = dv;
        }
        red_s[ty * 64 + tx * 4 + 0] = ps0;  red_q[ty * 64 + tx * 4 + 0] = pq0;
        red_s[ty * 64 + tx * 4 + 1] = ps1;  red_q[ty * 64 + tx * 4 + 1] = pq1;
        red_s[ty * 64 + tx * 4 + 2] = ps2;  red_q[ty * 64 + tx * 4 + 2] = pq2;
        red_s[ty * 64 + tx * 4 + 3] = ps3;  red_q[ty * 64 + tx * 4 + 3] = pq3;
        __syncthreads();

        // wave 0: reduce colstat partials over ty and fire atomics (no wait)
        if (tid < 64) {
            float ss = 0, qq = 0;
            #pragma unroll
            for (int r = 0; r < 16; ++r) {
                ss += red_s[r * 64 + tid];
                qq += red_q[r * 64 + tid];
            }
            atomicAdd(&ws[WS_COLSUM + kc + tid], ss);
            atomicAdd(&ws[WS_COLSQ + kc + tid], qq);
        }

        #pragma unroll 8
        for (int k = 0; k < 64; ++k) {
            float4 a4 = *reinterpret_cast<const float4*>(zsT + k * 68 + ty * 4);
            float4 b4 = *reinterpret_cast<const float4*>(dsm + k * 64 + tx * 4);
            float av[4] = {a4.x, a4.y, a4.z, a4.w};
            float bv[4] = {b4.x, b4.y, b4.z, b4.w};
            #pragma unroll
            for (int i = 0; i < 4; ++i)
                #pragma unroll
                for (int j = 0; j < 4; ++j)
                    acc[i][j] = fmaf(av[i], bv[j], acc[i][j]);
        }
        __syncthreads();
    }

    // write proj (coalesced float4 per row)
    #pragma unroll
    for (int i = 0; i < 4; ++i) {
        float4 v = {acc[i][0], acc[i][1], acc[i][2], acc[i][3]};
        *reinterpret_cast<float4*>(proj + (rowbase + ty * 4 + i) * S_DIM + tx * 4) = v;
    }

    // per-column partials for proj stats (fused epilogue)
    float cs[4] = {}, cq[4] = {};
    #pragma unroll
    for (int i = 0; i < 4; ++i)
        #pragma unroll
        for (int j = 0; j < 4; ++j) {
            cs[j] += acc[i][j];
            cq[j] = fmaf(acc[i][j], acc[i][j], cq[j]);
        }
    __syncthreads();               // safe to reuse red_s/red_q now
    #pragma unroll
    for (int j = 0; j < 4; ++j) {
        red_s[ty * 64 + tx * 4 + j] = cs[j];
        red_q[ty * 64 + tx * 4 + j] = cq[j];
    }
    __syncthreads();
    if (tid < 64) {
        float ssum = 0, qsum = 0;
        #pragma unroll
        for (int r = 0; r < 16; ++r) {
            ssum += red_s[r * 64 + tid];
            qsum += red_q[r * 64 + tid];
        }
        atomicAdd(&ws[WS_PSUM + tid], ssum);
        atomicAdd(&ws[WS_PSQ + tid],  qsum);
    }
}

// ------------------------------------------------------------------ ECF sums
// 1024 blocks (64 rows) x 256 threads; thread = (s = tid&63, r = tid>>6).
// mean/scale computed inline per block (dispatch boundary ordered the atomics).
// One sincos + 16 complex rotations per element (angle-addition recurrence).
__global__ __launch_bounds__(256) void ecf_kernel(float* __restrict__ ws) {
    const float* proj = ws + WS_PROJ;
    int tid = threadIdx.x;
    int s = tid & 63, r = tid >> 6;

    __shared__ float s_mean[64], s_scale[64];
    if (tid < 64) {
        float sum = ws[WS_PSUM + tid], sq = ws[WS_PSQ + tid];
        float mean = sum / (float)B_ROWS;
        float var = (sq - (float)B_ROWS * mean * mean) / (float)(B_ROWS - 1);
        var = fmaxf(var, 0.f);
        s_mean[tid]  = mean;
        s_scale[tid] = 1.0f / (sqrtf(var) + 1e-8f);
    }
    __syncthreads();
    float mean  = s_mean[s];
    float scale = s_scale[s];
    const float dt = 2.0f / 17.0f;

    float ar[T_PTS] = {}, ai[T_PTS] = {};
    size_t base = (size_t)blockIdx.x * 64;
    for (int i = 0; i < 16; ++i) {
        size_t row = base + i * 4 + r;
        float p  = proj[row * S_DIM + s];
        float ph = (p - mean) * scale;
        float a  = dt * ph;
        float s1, c1;
        __sincosf(a, &s1, &c1);
        float cc = c1, sn = s1;
        ar[0] += cc; ai[0] += sn;
        #pragma unroll
        for (int k = 1; k < T_PTS; ++k) {
            float cn = cc * c1 - sn * s1;
            sn = fmaf(sn, c1, cc * s1);
            cc = cn;
            ar[k] += cc; ai[k] += sn;
        }
    }

    // reduce r=1..3 partials into r=0 via LDS, then one atomic per (t,s)
    __shared__ float red[3 * 2 * T_PTS * 64];
    if (r > 0) {
        float* dst = red + (r - 1) * (2 * T_PTS * 64);
        #pragma unroll
        for (int k = 0; k < T_PTS; ++k) {
            dst[k * 64 + s]               = ar[k];
            dst[T_PTS * 64 + k * 64 + s]  = ai[k];
        }
    }
    __syncthreads();
    if (r == 0) {
        const int STRIDE = 2 * T_PTS * 64;
        #pragma unroll
        for (int k = 0; k < T_PTS; ++k) {
            float vr = ar[k] + red[k * 64 + s] + red[STRIDE + k * 64 + s]
                             + red[2 * STRIDE + k * 64 + s];
            float vi = ai[k] + red[T_PTS * 64 + k * 64 + s]
                             + red[STRIDE + T_PTS * 64 + k * 64 + s]
                             + red[2 * STRIDE + T_PTS * 64 + k * 64 + s];
            atomicAdd(&ws[WS_ECFR + k * 64 + s], vr);
            atomicAdd(&ws[WS_ECFI + k * 64 + s], vi);
        }
    }
}

// ------------------------------------------------------------------ final loss
__global__ __launch_bounds__(256) void loss_kernel(const float* __restrict__ ws,
                                                   float* __restrict__ out) {
    int tid = threadIdx.x;
    double local = 0.0;
    // var_floor
    for (int d = tid; d < D_DIM; d += 256) {
        double sum = (double)ws[WS_COLSUM + d];
        double sq  = (double)ws[WS_COLSQ + d];
        double mean = sum / 65536.0;
        double var  = (sq - 65536.0 * mean * mean) / 65535.0;
        if (var < 0) var = 0;
        double rl = 1.0 - sqrt(var);
        if (rl < 0) rl = 0;
        local += rl / 768.0;
    }
    // ECF part
    const double dt = 2.0 / 17.0;
    for (int idx = tid; idx < T_PTS * 64; idx += 256) {
        int i = idx >> 6;
        double t   = dt * (i + 1);
        double tcf = exp(-0.5 * t * t);
        double w   = (i == 0 || i == T_PTS - 1) ? dt * 0.5 : dt;
        double er = (double)ws[WS_ECFR + idx] / 65536.0;
        double ei = (double)ws[WS_ECFI + idx] / 65536.0;
        double term = er * er + ei * ei - 2.0 * er * tcf + tcf * tcf;
        local += w * term / 64.0;
    }
    __shared__ double red[256];
    red[tid] = local;
    __syncthreads();
    for (int off = 128; off > 0; off >>= 1) {
        if (tid < off) red[tid] += red[tid + off];
        __syncthreads();
    }
    if (tid == 0) out[0] = (float)red[0];
}

extern "C" void kernel_launch(void* const* d_in, const int* in_sizes, int n_in,
                              void* d_out, int out_size, void* d_ws, size_t ws_size,
                              hipStream_t stream) {
    const float* z    = (const float*)d_in[0];  // [65536, 768]
    const float* dirs = (const float*)d_in[1];  // [768, 64]
    float* out = (float*)d_out;                 // scalar fp32
    float* ws  = (float*)d_ws;                  // needs ~16.02 MiB

    norm_kernel<<<S_DIM, 64, 0, stream>>>(dirs, ws);        // also zeroes accums
    gemm_kernel<<<B_ROWS / 64, 256, 0, stream>>>(z, dirs, ws);
    ecf_kernel<<<B_ROWS / 64, 256, 0, stream>>>(ws);
    loss_kernel<<<1, 256, 0, stream>>>(ws, out);
}

// Round 3
// 350.871 us; speedup vs baseline: 1.2259x; 1.1335x over previous
//
#include <hip/hip_runtime.h>
#include <math.h>

// Problem constants
#define B_ROWS 65536
#define D_DIM  768
#define S_DIM  64
#define T_PTS  17

#define GEMM_BLOCKS  512    // 128 rows each
#define CSTAT_BLOCKS 1024   // 64 rows each

// Workspace layout (float offsets). Accumulators (zeroed by norm_kernel) in
// first 3840 floats; proj [65536 x 64] follows. Total ~16.02 MiB.
#define WS_COLSUM 0       // 768  : per-dim sum of z
#define WS_COLSQ  768     // 768  : per-dim sumsq of z
#define WS_PSUM   1536    // 64   : per-col sum of proj
#define WS_PSQ    1600    // 64   : per-col sumsq of proj
#define WS_ECFR   1664    // 17*64: sum cos
#define WS_ECFI   2752    // 17*64: sum sin  (ends at 3840)
#define WS_INVN   3840    // 64   : 1/||dir_col||
#define WS_PROJ   4096    // 65536*64

// ------------------------------------------- dirs norms + zero accumulators
__global__ void norm_kernel(const float* __restrict__ dirs, float* __restrict__ ws) {
    int s = blockIdx.x;
    int t = threadIdx.x;
    if (s < 60) ws[s * 64 + t] = 0.f;   // zero accumulators every call
    float sum = 0.f;
    #pragma unroll
    for (int j = 0; j < D_DIM / 64; ++j) {
        float v = dirs[(size_t)(t + j * 64) * S_DIM + s];
        sum += v * v;
    }
    #pragma unroll
    for (int off = 32; off > 0; off >>= 1)
        sum += __shfl_down(sum, off, 64);
    if (t == 0) ws[WS_INVN + s] = 1.0f / sqrtf(sum);
}

// ---------------------- main: gemm (blocks 0..511) + colstats (512..1535)
// gemm: 128x64 tile, 8x4 per thread. All LDS accesses phase-clean:
//   zs staged float4 row-major (distinct bank-groups per 8-lane phase),
//   A read as scalar b32 (16-lane broadcast), B read b128 (tx%8 distinct).
__global__ __launch_bounds__(256, 3) void main_kernel(const float* __restrict__ z,
                                                      const float* __restrict__ dirs,
                                                      float* __restrict__ ws) {
    int tid = threadIdx.x;

    if (blockIdx.x >= GEMM_BLOCKS) {
        // -------- per-dim z statistics (memory-bound, overlaps gemm blocks)
        size_t base = (size_t)(blockIdx.x - GEMM_BLOCKS) * 64 * D_DIM;
        float s0 = 0, s1 = 0, s2 = 0, q0 = 0, q1 = 0, q2 = 0;
        #pragma unroll 4
        for (int r = 0; r < 64; ++r) {
            const float* p = z + base + (size_t)r * D_DIM;
            float a = p[tid], b = p[tid + 256], c = p[tid + 512];
            s0 += a; q0 = fmaf(a, a, q0);
            s1 += b; q1 = fmaf(b, b, q1);
            s2 += c; q2 = fmaf(c, c, q2);
        }
        atomicAdd(&ws[WS_COLSUM + tid],       s0);
        atomicAdd(&ws[WS_COLSUM + tid + 256], s1);
        atomicAdd(&ws[WS_COLSUM + tid + 512], s2);
        atomicAdd(&ws[WS_COLSQ + tid],        q0);
        atomicAdd(&ws[WS_COLSQ + tid + 256],  q1);
        atomicAdd(&ws[WS_COLSQ + tid + 512],  q2);
        return;
    }

    // ------------------------------------------------------ gemm part
    __shared__ float zs[128 * 68];   // row-major z tile, padded stride 68
    __shared__ float dsm[64 * 64];   // [k][s] normalized dirs tile
    float* proj = ws + WS_PROJ;

    int tx = tid & 15, ty = tid >> 4;       // tx -> 4 cols, ty -> 8 rows
    size_t rowbase = (size_t)blockIdx.x * 128;

    float4 invn4 = *reinterpret_cast<const float4*>(ws + WS_INVN + tx * 4);
    float acc[8][4] = {};

    for (int c = 0; c < D_DIM / 64; ++c) {
        int kc = c * 64;
        #pragma unroll
        for (int j = 0; j < 8; ++j) {
            int rr = ty + 16 * j;
            *reinterpret_cast<float4*>(&zs[rr * 68 + tx * 4]) =
                *reinterpret_cast<const float4*>(z + (rowbase + rr) * D_DIM + kc + tx * 4);
        }
        #pragma unroll
        for (int j = 0; j < 4; ++j) {
            int rr = ty + 16 * j;
            float4 dv = *reinterpret_cast<const float4*>(
                dirs + (size_t)(kc + rr) * S_DIM + tx * 4);
            dv.x *= invn4.x; dv.y *= invn4.y; dv.z *= invn4.z; dv.w *= invn4.w;
            *reinterpret_cast<float4*>(&dsm[rr * 64 + tx * 4]) = dv;
        }
        __syncthreads();

        const float* zrow = zs + ty * 8 * 68;
        #pragma unroll 4
        for (int k = 0; k < 64; ++k) {
            float4 b4 = *reinterpret_cast<const float4*>(&dsm[k * 64 + tx * 4]);
            #pragma unroll
            for (int i = 0; i < 8; ++i) {
                float a = zrow[i * 68 + k];
                acc[i][0] = fmaf(a, b4.x, acc[i][0]);
                acc[i][1] = fmaf(a, b4.y, acc[i][1]);
                acc[i][2] = fmaf(a, b4.z, acc[i][2]);
                acc[i][3] = fmaf(a, b4.w, acc[i][3]);
            }
        }
        __syncthreads();
    }

    // write proj (coalesced float4 per row)
    #pragma unroll
    for (int i = 0; i < 8; ++i) {
        float4 v = {acc[i][0], acc[i][1], acc[i][2], acc[i][3]};
        *reinterpret_cast<float4*>(proj + (rowbase + ty * 8 + i) * S_DIM + tx * 4) = v;
    }

    // per-column partials for proj stats (fused epilogue)
    float cs[4] = {}, cq[4] = {};
    #pragma unroll
    for (int i = 0; i < 8; ++i)
        #pragma unroll
        for (int j = 0; j < 4; ++j) {
            cs[j] += acc[i][j];
            cq[j] = fmaf(acc[i][j], acc[i][j], cq[j]);
        }
    __syncthreads();               // safe to reuse zs now
    float* reds = zs;              // [16][64]
    float* redq = zs + 1024;
    #pragma unroll
    for (int j = 0; j < 4; ++j) {
        reds[ty * 64 + tx * 4 + j] = cs[j];
        redq[ty * 64 + tx * 4 + j] = cq[j];
    }
    __syncthreads();
    if (tid < 64) {
        float ssum = 0, qsum = 0;
        #pragma unroll
        for (int r = 0; r < 16; ++r) {
            ssum += reds[r * 64 + tid];
            qsum += redq[r * 64 + tid];
        }
        atomicAdd(&ws[WS_PSUM + tid], ssum);
        atomicAdd(&ws[WS_PSQ + tid],  qsum);
    }
}

// ------------------------------------------------------------------ ECF sums
__global__ __launch_bounds__(256) void ecf_kernel(float* __restrict__ ws) {
    const float* proj = ws + WS_PROJ;
    int tid = threadIdx.x;
    int s = tid & 63, r = tid >> 6;

    __shared__ float s_mean[64], s_scale[64];
    if (tid < 64) {
        float sum = ws[WS_PSUM + tid], sq = ws[WS_PSQ + tid];
        float mean = sum / (float)B_ROWS;
        float var = (sq - (float)B_ROWS * mean * mean) / (float)(B_ROWS - 1);
        var = fmaxf(var, 0.f);
        s_mean[tid]  = mean;
        s_scale[tid] = 1.0f / (sqrtf(var) + 1e-8f);
    }
    __syncthreads();
    float mean  = s_mean[s];
    float scale = s_scale[s];
    const float dt = 2.0f / 17.0f;

    float ar[T_PTS] = {}, ai[T_PTS] = {};
    size_t base = (size_t)blockIdx.x * 64;
    for (int i = 0; i < 16; ++i) {
        size_t row = base + i * 4 + r;
        float p  = proj[row * S_DIM + s];
        float ph = (p - mean) * scale;
        float a  = dt * ph;
        float s1, c1;
        __sincosf(a, &s1, &c1);
        float cc = c1, sn = s1;
        ar[0] += cc; ai[0] += sn;
        #pragma unroll
        for (int k = 1; k < T_PTS; ++k) {
            float cn = cc * c1 - sn * s1;
            sn = fmaf(sn, c1, cc * s1);
            cc = cn;
            ar[k] += cc; ai[k] += sn;
        }
    }

    __shared__ float red[3 * 2 * T_PTS * 64];
    if (r > 0) {
        float* dst = red + (r - 1) * (2 * T_PTS * 64);
        #pragma unroll
        for (int k = 0; k < T_PTS; ++k) {
            dst[k * 64 + s]               = ar[k];
            dst[T_PTS * 64 + k * 64 + s]  = ai[k];
        }
    }
    __syncthreads();
    if (r == 0) {
        const int STRIDE = 2 * T_PTS * 64;
        #pragma unroll
        for (int k = 0; k < T_PTS; ++k) {
            float vr = ar[k] + red[k * 64 + s] + red[STRIDE + k * 64 + s]
                             + red[2 * STRIDE + k * 64 + s];
            float vi = ai[k] + red[T_PTS * 64 + k * 64 + s]
                             + red[STRIDE + T_PTS * 64 + k * 64 + s]
                             + red[2 * STRIDE + T_PTS * 64 + k * 64 + s];
            atomicAdd(&ws[WS_ECFR + k * 64 + s], vr);
            atomicAdd(&ws[WS_ECFI + k * 64 + s], vi);
        }
    }
}

// ------------------------------------------------------------------ final loss
__global__ __launch_bounds__(256) void loss_kernel(const float* __restrict__ ws,
                                                   float* __restrict__ out) {
    int tid = threadIdx.x;
    double local = 0.0;
    for (int d = tid; d < D_DIM; d += 256) {
        double sum = (double)ws[WS_COLSUM + d];
        double sq  = (double)ws[WS_COLSQ + d];
        double mean = sum / 65536.0;
        double var  = (sq - 65536.0 * mean * mean) / 65535.0;
        if (var < 0) var = 0;
        double rl = 1.0 - sqrt(var);
        if (rl < 0) rl = 0;
        local += rl / 768.0;
    }
    const double dt = 2.0 / 17.0;
    for (int idx = tid; idx < T_PTS * 64; idx += 256) {
        int i = idx >> 6;
        double t   = dt * (i + 1);
        double tcf = exp(-0.5 * t * t);
        double w   = (i == 0 || i == T_PTS - 1) ? dt * 0.5 : dt;
        double er = (double)ws[WS_ECFR + idx] / 65536.0;
        double ei = (double)ws[WS_ECFI + idx] / 65536.0;
        double term = er * er + ei * ei - 2.0 * er * tcf + tcf * tcf;
        local += w * term / 64.0;
    }
    __shared__ double red[256];
    red[tid] = local;
    __syncthreads();
    for (int off = 128; off > 0; off >>= 1) {
        if (tid < off) red[tid] += red[tid + off];
        __syncthreads();
    }
    if (tid == 0) out[0] = (float)red[0];
}

extern "C" void kernel_launch(void* const* d_in, const int* in_sizes, int n_in,
                              void* d_out, int out_size, void* d_ws, size_t ws_size,
                              hipStream_t stream) {
    const float* z    = (const float*)d_in[0];  // [65536, 768]
    const float* dirs = (const float*)d_in[1];  // [768, 64]
    float* out = (float*)d_out;                 // scalar fp32
    float* ws  = (float*)d_ws;                  // needs ~16.02 MiB

    norm_kernel<<<S_DIM, 64, 0, stream>>>(dirs, ws);        // also zeroes accums
    main_kernel<<<GEMM_BLOCKS + CSTAT_BLOCKS, 256, 0, stream>>>(z, dirs, ws);
    ecf_kernel<<<B_ROWS / 64, 256, 0, stream>>>(ws);
    loss_kernel<<<1, 256, 0, stream>>>(ws, out);
}

// Round 4
// 336.245 us; speedup vs baseline: 1.2792x; 1.0435x over previous
//
#include <hip/hip_runtime.h>
#include <math.h>

// Problem constants
#define B_ROWS 65536
#define D_DIM  768
#define S_DIM  64
#define T_PTS  17

// Workspace layout. Accumulators (zeroed by norm_kernel) in first 3840 floats.
#define WS_COLSUM 0       // 768  : per-dim sum of z
#define WS_COLSQ  768     // 768  : per-dim sumsq of z
#define WS_PSUM   1536    // 64   : per-col sum of proj
#define WS_PSQ    1600    // 64   : per-col sumsq of proj
#define WS_ECFR   1664    // 17*64: sum cos
#define WS_ECFI   2752    // 17*64: sum sin (ends 3840)
#define WS_BT_HI_S 7680   // SHORT offset (== float offset 3840): bT_hi[64][768] bf16
#define WS_BT_LO_S 56832  // SHORT offset: bT_lo[64][768] bf16
#define WS_PROJ   53248   // float offset: proj [65536 x 64]

typedef __attribute__((ext_vector_type(8))) short short8;   // 8 bf16 = 4 VGPR
typedef __attribute__((ext_vector_type(4))) short short4v;  // 4 bf16 = 2 VGPR
typedef __attribute__((ext_vector_type(4))) float float4v;

#define MFMA_BF16 __builtin_amdgcn_mfma_f32_16x16x32_bf16

static __device__ inline unsigned short f2bf(float x) {   // RNE fp32->bf16
    unsigned u = __float_as_uint(x);
    u += 0x7FFFu + ((u >> 16) & 1u);
    return (unsigned short)(u >> 16);
}
static __device__ inline float bf2f(unsigned short h) {
    return __uint_as_float(((unsigned)h) << 16);
}

// ---------------- dirs: normalize, split to bf16 hi/lo, TRANSPOSE to [s][k];
// also zero the accumulator region. 64 blocks x 64 threads.
__global__ void norm_kernel(const float* __restrict__ dirs, float* __restrict__ ws) {
    int s = blockIdx.x;
    int t = threadIdx.x;
    if (s < 60) ws[s * 64 + t] = 0.f;   // zero accums 0..3839 every call

    float sum = 0.f;
    #pragma unroll
    for (int j = 0; j < 12; ++j) {
        float v = dirs[(size_t)(t + j * 64) * S_DIM + s];
        sum += v * v;
    }
    #pragma unroll
    for (int m = 32; m; m >>= 1) sum += __shfl_xor(sum, m, 64);
    float invn = 1.0f / sqrtf(sum);

    unsigned short* bt_hi = (unsigned short*)ws + WS_BT_HI_S;
    unsigned short* bt_lo = (unsigned short*)ws + WS_BT_LO_S;
    #pragma unroll
    for (int j = 0; j < 12; ++j) {
        int k = t + j * 64;
        float v = dirs[(size_t)k * S_DIM + s] * invn;
        unsigned short hi = f2bf(v);
        unsigned short lo = f2bf(v - bf2f(hi));
        bt_hi[s * D_DIM + k] = hi;
        bt_lo[s * D_DIM + k] = lo;
    }
}

// ---------------- main: split-bf16 MFMA GEMM (proj = z @ dn) + fused colstats
// 512 blocks x 256 threads (4 waves). Block tile: 128 rows x 64 s, BK=64.
// LDS stride 72 bf16 (144 B) -> all 32 banks used on b128 frag reads.
__global__ __launch_bounds__(256, 2) void main_kernel(const float* __restrict__ z,
                                                      float* __restrict__ ws) {
    __shared__ __align__(16) short zs_hi[128 * 72];
    __shared__ __align__(16) short zs_lo[128 * 72];
    __shared__ __align__(16) short bs_hi[64 * 72];
    __shared__ __align__(16) short bs_lo[64 * 72];
    __shared__ __align__(16) float cbuf[2 * 64 * 17];   // colstat partials / epi reuse

    const unsigned short* bt_hi = (const unsigned short*)ws + WS_BT_HI_S;
    const unsigned short* bt_lo = (const unsigned short*)ws + WS_BT_LO_S;
    float* proj = ws + WS_PROJ;

    int tid = threadIdx.x;
    int tx = tid & 15, ty = tid >> 4;        // staging: tx -> 4 k, ty + 16j -> rows
    int l = tid & 63, l15 = l & 15, q = l >> 4;
    int waveId = tid >> 6;
    int waveRow = waveId * 32;               // each wave: 32 rows x 64 s
    size_t rowbase = (size_t)blockIdx.x * 128;

    float4v acc[2][4] = {};                  // [rowtile][stile], D-layout fp32

    for (int c = 0; c < D_DIM / 64; ++c) {
        int kc = c * 64;

        // ---- stage z tile: fp32 -> bf16 hi/lo, + colstat register partials
        float ps0 = 0, ps1 = 0, ps2 = 0, ps3 = 0;
        float pq0 = 0, pq1 = 0, pq2 = 0, pq3 = 0;
        #pragma unroll
        for (int j = 0; j < 8; ++j) {
            int rr = ty + 16 * j;
            float4 v = *reinterpret_cast<const float4*>(
                z + (rowbase + rr) * D_DIM + kc + tx * 4);
            ps0 += v.x; pq0 = fmaf(v.x, v.x, pq0);
            ps1 += v.y; pq1 = fmaf(v.y, v.y, pq1);
            ps2 += v.z; pq2 = fmaf(v.z, v.z, pq2);
            ps3 += v.w; pq3 = fmaf(v.w, v.w, pq3);
            short4v h4, l4;
            h4.x = (short)f2bf(v.x); l4.x = (short)f2bf(v.x - bf2f((unsigned short)h4.x));
            h4.y = (short)f2bf(v.y); l4.y = (short)f2bf(v.y - bf2f((unsigned short)h4.y));
            h4.z = (short)f2bf(v.z); l4.z = (short)f2bf(v.z - bf2f((unsigned short)h4.z));
            h4.w = (short)f2bf(v.w); l4.w = (short)f2bf(v.w - bf2f((unsigned short)h4.w));
            *reinterpret_cast<short4v*>(&zs_hi[rr * 72 + tx * 4]) = h4;
            *reinterpret_cast<short4v*>(&zs_lo[rr * 72 + tx * 4]) = l4;
        }
        // colstat partials -> padded LDS (stride 17 breaks bank pathology)
        cbuf[(tx * 4 + 0) * 17 + ty] = ps0;  cbuf[1088 + (tx * 4 + 0) * 17 + ty] = pq0;
        cbuf[(tx * 4 + 1) * 17 + ty] = ps1;  cbuf[1088 + (tx * 4 + 1) * 17 + ty] = pq1;
        cbuf[(tx * 4 + 2) * 17 + ty] = ps2;  cbuf[1088 + (tx * 4 + 2) * 17 + ty] = pq2;
        cbuf[(tx * 4 + 3) * 17 + ty] = ps3;  cbuf[1088 + (tx * 4 + 3) * 17 + ty] = pq3;

        // ---- stage B tile (precomputed bf16, transposed [s][k]) : b128 copies
        {
            int srow = tid >> 2;
            int kpart = (tid & 3) * 16;
            short8 b0 = *(const short8*)(bt_hi + (size_t)srow * D_DIM + kc + kpart);
            short8 b1 = *(const short8*)(bt_hi + (size_t)srow * D_DIM + kc + kpart + 8);
            short8 c0 = *(const short8*)(bt_lo + (size_t)srow * D_DIM + kc + kpart);
            short8 c1 = *(const short8*)(bt_lo + (size_t)srow * D_DIM + kc + kpart + 8);
            *(short8*)&bs_hi[srow * 72 + kpart]     = b0;
            *(short8*)&bs_hi[srow * 72 + kpart + 8] = b1;
            *(short8*)&bs_lo[srow * 72 + kpart]     = c0;
            *(short8*)&bs_lo[srow * 72 + kpart + 8] = c1;
        }
        __syncthreads();

        // ---- colstat reduce (waves 0-1) overlapped with MFMA phase
        if (tid < 128) {
            int which = tid >> 6, kcol = tid & 63;
            const float* src = cbuf + which * 1088 + kcol * 17;
            float v = 0.f;
            #pragma unroll
            for (int r = 0; r < 16; ++r) v += src[r];
            atomicAdd(&ws[(which ? WS_COLSQ : WS_COLSUM) + kc + kcol], v);
        }

        // ---- MFMA phase: A-frags (hi/lo x 2 rowtiles x 2 ksteps), B per stile
        short8 ah[2][2], al[2][2];
        #pragma unroll
        for (int rt = 0; rt < 2; ++rt) {
            int aoff = (waveRow + rt * 16 + l15) * 72 + q * 8;
            ah[rt][0] = *(const short8*)&zs_hi[aoff];
            ah[rt][1] = *(const short8*)&zs_hi[aoff + 32];
            al[rt][0] = *(const short8*)&zs_lo[aoff];
            al[rt][1] = *(const short8*)&zs_lo[aoff + 32];
        }
        #pragma unroll
        for (int st = 0; st < 4; ++st) {
            int boff = (st * 16 + l15) * 72 + q * 8;
            short8 bh0 = *(const short8*)&bs_hi[boff];
            short8 bh1 = *(const short8*)&bs_hi[boff + 32];
            short8 bl0 = *(const short8*)&bs_lo[boff];
            short8 bl1 = *(const short8*)&bs_lo[boff + 32];
            #pragma unroll
            for (int rt = 0; rt < 2; ++rt) {
                acc[rt][st] = MFMA_BF16(ah[rt][0], bh0, acc[rt][st], 0, 0, 0);
                acc[rt][st] = MFMA_BF16(al[rt][0], bh0, acc[rt][st], 0, 0, 0);
                acc[rt][st] = MFMA_BF16(ah[rt][0], bl0, acc[rt][st], 0, 0, 0);
                acc[rt][st] = MFMA_BF16(ah[rt][1], bh1, acc[rt][st], 0, 0, 0);
                acc[rt][st] = MFMA_BF16(al[rt][1], bh1, acc[rt][st], 0, 0, 0);
                acc[rt][st] = MFMA_BF16(ah[rt][1], bl1, acc[rt][st], 0, 0, 0);
            }
        }
        __syncthreads();
    }

    // ---- epilogue: proj write (D layout: row=(l>>4)*4+reg, col=l&15)
    #pragma unroll
    for (int rt = 0; rt < 2; ++rt)
        #pragma unroll
        for (int st = 0; st < 4; ++st) {
            int col = st * 16 + l15;
            size_t rbase = rowbase + waveRow + rt * 16 + q * 4;
            float4v v = acc[rt][st];
            proj[(rbase + 0) * S_DIM + col] = v[0];
            proj[(rbase + 1) * S_DIM + col] = v[1];
            proj[(rbase + 2) * S_DIM + col] = v[2];
            proj[(rbase + 3) * S_DIM + col] = v[3];
        }

    // ---- proj column stats: per-lane partials -> LDS -> 128-thread reduce
    float* red = cbuf;   // reuse (2*64*16 = 2048 <= 2176)
    #pragma unroll
    for (int st = 0; st < 4; ++st) {
        float cs = 0.f, cq = 0.f;
        #pragma unroll
        for (int rt = 0; rt < 2; ++rt) {
            float4v v = acc[rt][st];
            cs += v[0] + v[1] + v[2] + v[3];
            cq += v[0]*v[0] + v[1]*v[1] + v[2]*v[2] + v[3]*v[3];
        }
        int s = st * 16 + l15;
        int slot = waveId * 4 + q;
        red[(0 * 64 + s) * 16 + slot] = cs;
        red[(1 * 64 + s) * 16 + slot] = cq;
    }
    __syncthreads();
    if (tid < 128) {
        int which = tid >> 6, s = tid & 63;
        const float* src = red + (which * 64 + s) * 16;
        float v = 0.f;
        #pragma unroll
        for (int r = 0; r < 16; ++r) v += src[r];
        atomicAdd(&ws[(which ? WS_PSQ : WS_PSUM) + s], v);
    }
}

// ------------------------------------------------------------------ ECF sums
__global__ __launch_bounds__(256) void ecf_kernel(float* __restrict__ ws) {
    const float* proj = ws + WS_PROJ;
    int tid = threadIdx.x;
    int s = tid & 63, r = tid >> 6;

    __shared__ float s_mean[64], s_scale[64];
    if (tid < 64) {
        float sum = ws[WS_PSUM + tid], sq = ws[WS_PSQ + tid];
        float mean = sum / (float)B_ROWS;
        float var = (sq - (float)B_ROWS * mean * mean) / (float)(B_ROWS - 1);
        var = fmaxf(var, 0.f);
        s_mean[tid]  = mean;
        s_scale[tid] = 1.0f / (sqrtf(var) + 1e-8f);
    }
    __syncthreads();
    float mean  = s_mean[s];
    float scale = s_scale[s];
    const float dt = 2.0f / 17.0f;

    float ar[T_PTS] = {}, ai[T_PTS] = {};
    size_t base = (size_t)blockIdx.x * 64;
    for (int i = 0; i < 16; ++i) {
        size_t row = base + i * 4 + r;
        float p  = proj[row * S_DIM + s];
        float ph = (p - mean) * scale;
        float a  = dt * ph;
        float s1, c1;
        __sincosf(a, &s1, &c1);
        float cc = c1, sn = s1;
        ar[0] += cc; ai[0] += sn;
        #pragma unroll
        for (int k = 1; k < T_PTS; ++k) {
            float cn = cc * c1 - sn * s1;
            sn = fmaf(sn, c1, cc * s1);
            cc = cn;
            ar[k] += cc; ai[k] += sn;
        }
    }

    __shared__ float red[3 * 2 * T_PTS * 64];
    if (r > 0) {
        float* dst = red + (r - 1) * (2 * T_PTS * 64);
        #pragma unroll
        for (int k = 0; k < T_PTS; ++k) {
            dst[k * 64 + s]               = ar[k];
            dst[T_PTS * 64 + k * 64 + s]  = ai[k];
        }
    }
    __syncthreads();
    if (r == 0) {
        const int STRIDE = 2 * T_PTS * 64;
        #pragma unroll
        for (int k = 0; k < T_PTS; ++k) {
            float vr = ar[k] + red[k * 64 + s] + red[STRIDE + k * 64 + s]
                             + red[2 * STRIDE + k * 64 + s];
            float vi = ai[k] + red[T_PTS * 64 + k * 64 + s]
                             + red[STRIDE + T_PTS * 64 + k * 64 + s]
                             + red[2 * STRIDE + T_PTS * 64 + k * 64 + s];
            atomicAdd(&ws[WS_ECFR + k * 64 + s], vr);
            atomicAdd(&ws[WS_ECFI + k * 64 + s], vi);
        }
    }
}

// ------------------------------------------------------------------ final loss
__global__ __launch_bounds__(256) void loss_kernel(const float* __restrict__ ws,
                                                   float* __restrict__ out) {
    int tid = threadIdx.x;
    double local = 0.0;
    for (int d = tid; d < D_DIM; d += 256) {
        double sum = (double)ws[WS_COLSUM + d];
        double sq  = (double)ws[WS_COLSQ + d];
        double mean = sum / 65536.0;
        double var  = (sq - 65536.0 * mean * mean) / 65535.0;
        if (var < 0) var = 0;
        double rl = 1.0 - sqrt(var);
        if (rl < 0) rl = 0;
        local += rl / 768.0;
    }
    const double dt = 2.0 / 17.0;
    for (int idx = tid; idx < T_PTS * 64; idx += 256) {
        int i = idx >> 6;
        double t   = dt * (i + 1);
        double tcf = exp(-0.5 * t * t);
        double w   = (i == 0 || i == T_PTS - 1) ? dt * 0.5 : dt;
        double er = (double)ws[WS_ECFR + idx] / 65536.0;
        double ei = (double)ws[WS_ECFI + idx] / 65536.0;
        double term = er * er + ei * ei - 2.0 * er * tcf + tcf * tcf;
        local += w * term / 64.0;
    }
    __shared__ double red[256];
    red[tid] = local;
    __syncthreads();
    for (int off = 128; off > 0; off >>= 1) {
        if (tid < off) red[tid] += red[tid + off];
        __syncthreads();
    }
    if (tid == 0) out[0] = (float)red[0];
}

extern "C" void kernel_launch(void* const* d_in, const int* in_sizes, int n_in,
                              void* d_out, int out_size, void* d_ws, size_t ws_size,
                              hipStream_t stream) {
    const float* z    = (const float*)d_in[0];  // [65536, 768]
    const float* dirs = (const float*)d_in[1];  // [768, 64]
    float* out = (float*)d_out;                 // scalar fp32
    float* ws  = (float*)d_ws;                  // ~16.3 MiB used

    norm_kernel<<<S_DIM, 64, 0, stream>>>(dirs, ws);   // zero accums + split/transpose B
    main_kernel<<<B_ROWS / 128, 256, 0, stream>>>(z, ws);
    ecf_kernel<<<B_ROWS / 64, 256, 0, stream>>>(ws);
    loss_kernel<<<1, 256, 0, stream>>>(ws, out);
}

// Round 5
// 331.588 us; speedup vs baseline: 1.2972x; 1.0140x over previous
//
#include <hip/hip_runtime.h>
#include <math.h>

// Problem constants
#define B_ROWS 65536
#define D_DIM  768
#define S_DIM  64
#define T_PTS  17

// Workspace layout. Accumulators (zeroed by norm_kernel) in first 3840 floats.
#define WS_COLSUM 0       // 768  : per-dim sum of z
#define WS_COLSQ  768     // 768  : per-dim sumsq of z   (COLSUM..COLSQ contiguous 0..1535)
#define WS_PSUM   1536    // 64   : per-col sum of proj
#define WS_PSQ    1600    // 64   : per-col sumsq of proj
#define WS_ECFR   1664    // 17*64: sum cos
#define WS_ECFI   2752    // 17*64: sum sin (ends 3840)
#define WS_BT_HI_S 7680   // SHORT offset (== float offset 3840): bT_hi[64][768] bf16
#define WS_PROJ   53248   // float offset: proj [65536 x 64]

typedef __attribute__((ext_vector_type(8))) short short8;   // 8 bf16 = 4 VGPR
typedef __attribute__((ext_vector_type(4))) short short4v;  // 4 bf16 = 2 VGPR
typedef __attribute__((ext_vector_type(4))) float float4v;

#define MFMA_BF16 __builtin_amdgcn_mfma_f32_16x16x32_bf16

static __device__ inline unsigned short f2bf(float x) {   // RNE fp32->bf16
    unsigned u = __float_as_uint(x);
    u += 0x7FFFu + ((u >> 16) & 1u);
    return (unsigned short)(u >> 16);
}
static __device__ inline float bf2f(unsigned short h) {
    return __uint_as_float(((unsigned)h) << 16);
}

// ---------------- dirs: normalize, bf16 hi, TRANSPOSE to [s][k]; zero accums.
__global__ void norm_kernel(const float* __restrict__ dirs, float* __restrict__ ws) {
    int s = blockIdx.x;
    int t = threadIdx.x;
    if (s < 60) ws[s * 64 + t] = 0.f;   // zero accums 0..3839 every call

    float sum = 0.f;
    #pragma unroll
    for (int j = 0; j < 12; ++j) {
        float v = dirs[(size_t)(t + j * 64) * S_DIM + s];
        sum += v * v;
    }
    #pragma unroll
    for (int m = 32; m; m >>= 1) sum += __shfl_xor(sum, m, 64);
    float invn = 1.0f / sqrtf(sum);

    unsigned short* bt_hi = (unsigned short*)ws + WS_BT_HI_S;
    #pragma unroll
    for (int j = 0; j < 12; ++j) {
        int k = t + j * 64;
        float v = dirs[(size_t)k * S_DIM + s] * invn;
        bt_hi[s * D_DIM + k] = f2bf(v);
    }
}

// ---------------- main: 2-term split-bf16 MFMA GEMM + colstats (LDS-accumulated)
// 512 blocks x 256 threads (4 waves). Block tile: 128 rows x 64 s, BK=64.
// No global atomics inside the K-loop; A-tile register-prefetched across barrier.
__global__ __launch_bounds__(256, 2) void main_kernel(const float* __restrict__ z,
                                                      float* __restrict__ ws) {
    __shared__ __align__(16) short zs_hi[128 * 72];
    __shared__ __align__(16) short zs_lo[128 * 72];
    __shared__ __align__(16) short bs[64 * 72];
    __shared__ float colacc[1536];                 // per-block colstat accumulator
    __shared__ __align__(16) float cbuf[2 * 64 * 17];

    const unsigned short* bt_hi = (const unsigned short*)ws + WS_BT_HI_S;
    float* proj = ws + WS_PROJ;

    int tid = threadIdx.x;
    int tx = tid & 15, ty = tid >> 4;        // staging: tx -> 4 k, ty + 16j -> rows
    int l = tid & 63, l15 = l & 15, q = l >> 4;
    int waveId = tid >> 6;
    int waveRow = waveId * 32;               // each wave: 32 rows x 64 s
    size_t rowbase = (size_t)blockIdx.x * 128;

    // zero per-block colstat accumulator
    #pragma unroll
    for (int j = 0; j < 6; ++j) colacc[tid + j * 256] = 0.f;

    // preload A-tile c=0 into registers
    float4 av[8];
    #pragma unroll
    for (int j = 0; j < 8; ++j)
        av[j] = *reinterpret_cast<const float4*>(
            z + (rowbase + ty + 16 * j) * D_DIM + tx * 4);

    float4v acc[2][4] = {};                  // [rowtile][stile]

    for (int c = 0; c < D_DIM / 64; ++c) {
        int kc = c * 64;

        // B tile loads (L2-hot; 96 KB table total)
        int srow = tid >> 2;
        int kpart = (tid & 3) * 16;
        short8 b0 = *(const short8*)(bt_hi + (size_t)srow * D_DIM + kc + kpart);
        short8 b1 = *(const short8*)(bt_hi + (size_t)srow * D_DIM + kc + kpart + 8);

        // ---- stage A: cvt prefetched regs -> bf16 hi/lo, + colstat partials
        float ps0 = 0, ps1 = 0, ps2 = 0, ps3 = 0;
        float pq0 = 0, pq1 = 0, pq2 = 0, pq3 = 0;
        #pragma unroll
        for (int j = 0; j < 8; ++j) {
            float4 v = av[j];
            int rr = ty + 16 * j;
            ps0 += v.x; pq0 = fmaf(v.x, v.x, pq0);
            ps1 += v.y; pq1 = fmaf(v.y, v.y, pq1);
            ps2 += v.z; pq2 = fmaf(v.z, v.z, pq2);
            ps3 += v.w; pq3 = fmaf(v.w, v.w, pq3);
            short4v h4, l4;
            h4.x = (short)f2bf(v.x); l4.x = (short)f2bf(v.x - bf2f((unsigned short)h4.x));
            h4.y = (short)f2bf(v.y); l4.y = (short)f2bf(v.y - bf2f((unsigned short)h4.y));
            h4.z = (short)f2bf(v.z); l4.z = (short)f2bf(v.z - bf2f((unsigned short)h4.z));
            h4.w = (short)f2bf(v.w); l4.w = (short)f2bf(v.w - bf2f((unsigned short)h4.w));
            *reinterpret_cast<short4v*>(&zs_hi[rr * 72 + tx * 4]) = h4;
            *reinterpret_cast<short4v*>(&zs_lo[rr * 72 + tx * 4]) = l4;
        }
        cbuf[(tx * 4 + 0) * 17 + ty] = ps0;  cbuf[1088 + (tx * 4 + 0) * 17 + ty] = pq0;
        cbuf[(tx * 4 + 1) * 17 + ty] = ps1;  cbuf[1088 + (tx * 4 + 1) * 17 + ty] = pq1;
        cbuf[(tx * 4 + 2) * 17 + ty] = ps2;  cbuf[1088 + (tx * 4 + 2) * 17 + ty] = pq2;
        cbuf[(tx * 4 + 3) * 17 + ty] = ps3;  cbuf[1088 + (tx * 4 + 3) * 17 + ty] = pq3;

        *(short8*)&bs[srow * 72 + kpart]     = b0;
        *(short8*)&bs[srow * 72 + kpart + 8] = b1;
        __syncthreads();

        // ---- fire A-tile prefetch for next c (rides under the MFMA phase)
        int kn = (kc + 64 < D_DIM) ? kc + 64 : kc;   // last iter: harmless reload
        #pragma unroll
        for (int j = 0; j < 8; ++j)
            av[j] = *reinterpret_cast<const float4*>(
                z + (rowbase + ty + 16 * j) * D_DIM + kn + tx * 4);

        // ---- colstat reduce into LDS accumulator (single owner per address)
        if (tid < 128) {
            int which = tid >> 6, kcol = tid & 63;
            const float* src = cbuf + which * 1088 + kcol * 17;
            float v = 0.f;
            #pragma unroll
            for (int r = 0; r < 16; ++r) v += src[r];
            colacc[which * 768 + kc + kcol] += v;
        }

        // ---- MFMA phase (2-term: a_hi*b + a_lo*b)
        short8 ah[2][2], al[2][2];
        #pragma unroll
        for (int rt = 0; rt < 2; ++rt) {
            int aoff = (waveRow + rt * 16 + l15) * 72 + q * 8;
            ah[rt][0] = *(const short8*)&zs_hi[aoff];
            ah[rt][1] = *(const short8*)&zs_hi[aoff + 32];
            al[rt][0] = *(const short8*)&zs_lo[aoff];
            al[rt][1] = *(const short8*)&zs_lo[aoff + 32];
        }
        #pragma unroll
        for (int st = 0; st < 4; ++st) {
            int boff = (st * 16 + l15) * 72 + q * 8;
            short8 bh0 = *(const short8*)&bs[boff];
            short8 bh1 = *(const short8*)&bs[boff + 32];
            #pragma unroll
            for (int rt = 0; rt < 2; ++rt) {
                acc[rt][st] = MFMA_BF16(ah[rt][0], bh0, acc[rt][st], 0, 0, 0);
                acc[rt][st] = MFMA_BF16(al[rt][0], bh0, acc[rt][st], 0, 0, 0);
                acc[rt][st] = MFMA_BF16(ah[rt][1], bh1, acc[rt][st], 0, 0, 0);
                acc[rt][st] = MFMA_BF16(al[rt][1], bh1, acc[rt][st], 0, 0, 0);
            }
        }
        __syncthreads();
    }

    // ---- flush colstats to global: ONE atomic sweep per block (fire & forget)
    #pragma unroll
    for (int j = 0; j < 6; ++j) {
        int idx = tid + j * 256;             // maps 1:1 onto ws[0..1535]
        atomicAdd(&ws[idx], colacc[idx]);
    }

    // ---- epilogue: proj write (D layout: row=(l>>4)*4+reg, col=l&15)
    #pragma unroll
    for (int rt = 0; rt < 2; ++rt)
        #pragma unroll
        for (int st = 0; st < 4; ++st) {
            int col = st * 16 + l15;
            size_t rbase = rowbase + waveRow + rt * 16 + q * 4;
            float4v v = acc[rt][st];
            proj[(rbase + 0) * S_DIM + col] = v[0];
            proj[(rbase + 1) * S_DIM + col] = v[1];
            proj[(rbase + 2) * S_DIM + col] = v[2];
            proj[(rbase + 3) * S_DIM + col] = v[3];
        }

    // ---- proj column stats: per-lane partials -> LDS -> 128-thread reduce
    float* red = cbuf;   // safe: all cbuf reads retired before last barrier
    #pragma unroll
    for (int st = 0; st < 4; ++st) {
        float cs = 0.f, cq = 0.f;
        #pragma unroll
        for (int rt = 0; rt < 2; ++rt) {
            float4v v = acc[rt][st];
            cs += v[0] + v[1] + v[2] + v[3];
            cq += v[0]*v[0] + v[1]*v[1] + v[2]*v[2] + v[3]*v[3];
        }
        int s = st * 16 + l15;
        int slot = waveId * 4 + q;
        red[(0 * 64 + s) * 16 + slot] = cs;
        red[(1 * 64 + s) * 16 + slot] = cq;
    }
    __syncthreads();
    if (tid < 128) {
        int which = tid >> 6, s = tid & 63;
        const float* src = red + (which * 64 + s) * 16;
        float v = 0.f;
        #pragma unroll
        for (int r = 0; r < 16; ++r) v += src[r];
        atomicAdd(&ws[(which ? WS_PSQ : WS_PSUM) + s], v);
    }
}

// ------------------------------------------------------------------ ECF sums
__global__ __launch_bounds__(256) void ecf_kernel(float* __restrict__ ws) {
    const float* proj = ws + WS_PROJ;
    int tid = threadIdx.x;
    int s = tid & 63, r = tid >> 6;

    __shared__ float s_mean[64], s_scale[64];
    if (tid < 64) {
        float sum = ws[WS_PSUM + tid], sq = ws[WS_PSQ + tid];
        float mean = sum / (float)B_ROWS;
        float var = (sq - (float)B_ROWS * mean * mean) / (float)(B_ROWS - 1);
        var = fmaxf(var, 0.f);
        s_mean[tid]  = mean;
        s_scale[tid] = 1.0f / (sqrtf(var) + 1e-8f);
    }
    __syncthreads();
    float mean  = s_mean[s];
    float scale = s_scale[s];
    const float dt = 2.0f / 17.0f;

    float ar[T_PTS] = {}, ai[T_PTS] = {};
    size_t base = (size_t)blockIdx.x * 64;
    for (int i = 0; i < 16; ++i) {
        size_t row = base + i * 4 + r;
        float p  = proj[row * S_DIM + s];
        float ph = (p - mean) * scale;
        float a  = dt * ph;
        float s1, c1;
        __sincosf(a, &s1, &c1);
        float cc = c1, sn = s1;
        ar[0] += cc; ai[0] += sn;
        #pragma unroll
        for (int k = 1; k < T_PTS; ++k) {
            float cn = cc * c1 - sn * s1;
            sn = fmaf(sn, c1, cc * s1);
            cc = cn;
            ar[k] += cc; ai[k] += sn;
        }
    }

    __shared__ float red[3 * 2 * T_PTS * 64];
    if (r > 0) {
        float* dst = red + (r - 1) * (2 * T_PTS * 64);
        #pragma unroll
        for (int k = 0; k < T_PTS; ++k) {
            dst[k * 64 + s]               = ar[k];
            dst[T_PTS * 64 + k * 64 + s]  = ai[k];
        }
    }
    __syncthreads();
    if (r == 0) {
        const int STRIDE = 2 * T_PTS * 64;
        #pragma unroll
        for (int k = 0; k < T_PTS; ++k) {
            float vr = ar[k] + red[k * 64 + s] + red[STRIDE + k * 64 + s]
                             + red[2 * STRIDE + k * 64 + s];
            float vi = ai[k] + red[T_PTS * 64 + k * 64 + s]
                             + red[STRIDE + T_PTS * 64 + k * 64 + s]
                             + red[2 * STRIDE + T_PTS * 64 + k * 64 + s];
            atomicAdd(&ws[WS_ECFR + k * 64 + s], vr);
            atomicAdd(&ws[WS_ECFI + k * 64 + s], vi);
        }
    }
}

// ------------------------------------------------------------------ final loss
__global__ __launch_bounds__(256) void loss_kernel(const float* __restrict__ ws,
                                                   float* __restrict__ out) {
    int tid = threadIdx.x;
    double local = 0.0;
    for (int d = tid; d < D_DIM; d += 256) {
        double sum = (double)ws[WS_COLSUM + d];
        double sq  = (double)ws[WS_COLSQ + d];
        double mean = sum / 65536.0;
        double var  = (sq - 65536.0 * mean * mean) / 65535.0;
        if (var < 0) var = 0;
        double rl = 1.0 - sqrt(var);
        if (rl < 0) rl = 0;
        local += rl / 768.0;
    }
    const double dt = 2.0 / 17.0;
    for (int idx = tid; idx < T_PTS * 64; idx += 256) {
        int i = idx >> 6;
        double t   = dt * (i + 1);
        double tcf = exp(-0.5 * t * t);
        double w   = (i == 0 || i == T_PTS - 1) ? dt * 0.5 : dt;
        double er = (double)ws[WS_ECFR + idx] / 65536.0;
        double ei = (double)ws[WS_ECFI + idx] / 65536.0;
        double term = er * er + ei * ei - 2.0 * er * tcf + tcf * tcf;
        local += w * term / 64.0;
    }
    __shared__ double red[256];
    red[tid] = local;
    __syncthreads();
    for (int off = 128; off > 0; off >>= 1) {
        if (tid < off) red[tid] += red[tid + off];
        __syncthreads();
    }
    if (tid == 0) out[0] = (float)red[0];
}

extern "C" void kernel_launch(void* const* d_in, const int* in_sizes, int n_in,
                              void* d_out, int out_size, void* d_ws, size_t ws_size,
                              hipStream_t stream) {
    const float* z    = (const float*)d_in[0];  // [65536, 768]
    const float* dirs = (const float*)d_in[1];  // [768, 64]
    float* out = (float*)d_out;                 // scalar fp32
    float* ws  = (float*)d_ws;

    norm_kernel<<<S_DIM, 64, 0, stream>>>(dirs, ws);   // zero accums + bf16/transpose B
    main_kernel<<<B_ROWS / 128, 256, 0, stream>>>(z, ws);
    ecf_kernel<<<B_ROWS / 64, 256, 0, stream>>>(ws);
    loss_kernel<<<1, 256, 0, stream>>>(ws, out);
}